// Round 5
// baseline (211.637 us; speedup 1.0000x reference)
//
#include <hip/hip_runtime.h>
#include <hip/hip_bf16.h>
#include <math.h>

typedef __bf16 bf16;
typedef __bf16 bf16x8 __attribute__((ext_vector_type(8)));
typedef __bf16 bf16x4 __attribute__((ext_vector_type(4)));
typedef float f32x4 __attribute__((ext_vector_type(4)));
typedef short s16x4 __attribute__((ext_vector_type(4)));

#define MFMA16(a, b, c) __builtin_amdgcn_mfma_f32_16x16x32_bf16((a), (b), (c), 0, 0, 0)
// K=16 bf16 MFMA: B-frag layout B[k=g*4+j][col=c15] matches QK^T C-layout directly.
#define MFMA16K16(a, b, c) __builtin_amdgcn_mfma_f32_16x16x16bf16_1k((a), (b), (c), 0, 0, 0)
#define EXP2F(x) __builtin_amdgcn_exp2f(x)  // v_exp_f32: computes 2^x

// async global->LDS, 16B per lane; LDS dest = (wave-uniform) base + lane*16
__device__ __forceinline__ void gl_lds16(const bf16* g, bf16* l) {
  __builtin_amdgcn_global_load_lds(
      (const __attribute__((address_space(1))) void*)g,
      (__attribute__((address_space(3))) void*)l, 16, 0, 0);
}

// problem dims
static constexpr int B_N = 2, S_N = 2048, DM = 1024, H_N = 16, DK = 64;
static constexpr int M_N = B_N * S_N;             // 4096
static constexpr size_t NX = (size_t)M_N * DM;    // 4M elements
static constexpr size_t NW = (size_t)DM * DM;     // 1M elements
// workspace layout (bf16 elements)
static constexpr size_t OFF_X = 0;
static constexpr size_t OFF_W = NX;               // Wq,Wk,Wv,Wo
static constexpr size_t OFF_Q = OFF_W + 4 * NW;   // Q [b,h,s,d] (pre-scaled by log2e/8, roped)
static constexpr size_t OFF_K = OFF_Q + NX;       // K [b,h,s,d] (roped)
static constexpr size_t OFF_V = OFF_K + NX;       // V^T [b,h,d,s]
static constexpr size_t OFF_C = OFF_V + NX;       // ctx [b,s,h*d]; rope table aliases its head
// total 24M bf16 = 48 MB

// ---------------- fp32 -> bf16 cast + RoPE table (fused) ----------------
__global__ __launch_bounds__(256) void cast_all(
    const float* __restrict__ x, const float* __restrict__ wq,
    const float* __restrict__ wk, const float* __restrict__ wv,
    const float* __restrict__ wo, bf16* __restrict__ dst,
    float2* __restrict__ tab) {
  size_t i = ((size_t)blockIdx.x * 256 + threadIdx.x) * 4;
  const float* src;
  size_t off;
  if (i < NX) {
    src = x; off = i;
  } else {
    size_t e = i - NX;
    int wi = (int)(e >> 20);
    src = (wi == 0) ? wq : (wi == 1) ? wk : (wi == 2) ? wv : wo;
    off = e & (NW - 1);
  }
  float4 v = *(const float4*)(src + off);
  bf16x4 o = {(bf16)v.x, (bf16)v.y, (bf16)v.z, (bf16)v.w};
  *(bf16x4*)(dst + i) = o;
  if (blockIdx.x < 256) {
    int t = blockIdx.x * 256 + threadIdx.x;  // 65536 entries
    int s = t >> 5, j = t & 31;
    float invf = powf(10000.f, -(float)(2 * j) / 64.f);
    float sn, cs;
    sincosf((float)s * invf, &sn, &cs);
    tab[t] = make_float2(cs, sn);
  }
}

// ---------------- QKV GEMM (M=4096,N=3072,K=1024) + fused RoPE, V written transposed ----------------
__global__ __launch_bounds__(256) void gemm_qkv_rope(
    const bf16* __restrict__ X, const bf16* __restrict__ W3,
    const int* __restrict__ pos_ids, const float2* __restrict__ tab,
    bf16* __restrict__ Qo, bf16* __restrict__ Ko, bf16* __restrict__ Vt) {
  __shared__ __align__(16) bf16 As[128 * 32];
  __shared__ __align__(16) bf16 Bs[128 * 32];
  const int tid = threadIdx.x;
  const int wave = tid >> 6, lane = tid & 63;
  const int c15 = lane & 15, g = lane >> 4;
  const int mw = (wave & 1) * 64, nw = (wave >> 1) * 64;
  const int row0 = blockIdx.x * 128;
  const int n0 = blockIdx.y * 128;
  const bf16* Asrc = X + (size_t)row0 * DM;
  const bf16* Bsrc = W3 + (size_t)n0 * DM;
  const int srA = wave * 32 + (lane >> 2);
  const int cph = lane & 3;

  f32x4 acc[4][4] = {};
  for (int kt = 0; kt < DM / 32; ++kt) {
    const int k0 = kt * 32;
    __syncthreads();
#pragma unroll
    for (int c = 0; c < 2; ++c) {
      const int r = srA + c * 16;
      gl_lds16(Asrc + (size_t)r * DM + k0 + cph * 8, &As[wave * 1024 + c * 512]);
      gl_lds16(Bsrc + (size_t)r * DM + k0 + cph * 8, &Bs[wave * 1024 + c * 512]);
    }
    __syncthreads();
    bf16x8 af[4], bfr[4];
#pragma unroll
    for (int t = 0; t < 4; ++t)
      af[t] = *(const bf16x8*)&As[(mw + t * 16 + c15) * 32 + g * 8];
#pragma unroll
    for (int t = 0; t < 4; ++t)
      bfr[t] = *(const bf16x8*)&Bs[(nw + t * 16 + c15) * 32 + g * 8];
#pragma unroll
    for (int mt = 0; mt < 4; ++mt)
#pragma unroll
      for (int nt = 0; nt < 4; ++nt)
        acc[mt][nt] = MFMA16(af[mt], bfr[nt], acc[mt][nt]);
  }

  // epilogue: C/D col = nt*16+c15, row = g*4+r
  const int Wsel = n0 >> 10;             // 0=q, 1=k, 2=v
  const int colbase = (n0 & 1023) + nw;  // multiple of 64 -> one head
  const int h = colbase >> 6;
  if (Wsel == 2) {
#pragma unroll
    for (int mt = 0; mt < 4; ++mt) {
      const int srow = row0 + mw + mt * 16 + g * 4;
      const int bb = srow >> 11, ss = srow & 2047;
      const size_t vb = ((size_t)(bb * H_N + h) * DK) * S_N + ss;
#pragma unroll
      for (int nt = 0; nt < 4; ++nt) {
        bf16x4 v4;
#pragma unroll
        for (int r = 0; r < 4; ++r) v4[r] = (bf16)acc[mt][nt][r];
        *(bf16x4*)&Vt[vb + (size_t)(nt * 16 + c15) * S_N] = v4;
      }
    }
  } else {
    bf16* dst = (Wsel == 0) ? Qo : Ko;
    // Q pre-scale folds 1/sqrt(64) AND log2(e) so flash can use exp2 directly.
    const float sc = (Wsel == 0) ? 0.125f * 1.44269504088896f : 1.0f;
#pragma unroll
    for (int mt = 0; mt < 4; ++mt) {
#pragma unroll
      for (int r = 0; r < 4; ++r) {
        const int row = row0 + mw + mt * 16 + g * 4 + r;
        const int bb = row >> 11, ss = row & 2047;
        const int pos = pos_ids[row];
        const float2 c0 = tab[pos * 32 + c15];       // freq j = c15
        const float2 c1 = tab[pos * 32 + 16 + c15];  // freq j = 16+c15
        const size_t base = ((size_t)(bb * H_N + h) * S_N + ss) * DK;
#pragma unroll
        for (int ntp = 0; ntp < 2; ++ntp) {
          float x1 = acc[mt][ntp][r], x2 = acc[mt][ntp + 2][r];
          float cs = ntp ? c1.x : c0.x, sn = ntp ? c1.y : c0.y;
          dst[base + ntp * 16 + c15] = (bf16)((x1 * cs - x2 * sn) * sc);
          dst[base + ntp * 16 + c15 + 32] = (bf16)((x2 * cs + x1 * sn) * sc);
        }
      }
    }
  }
}

// ---------------- flash attention: 8 waves = (qh: 2 x 64-q) x (ky: 4 x 16-key slice) ----------------
// R11: 8 waves doubled occupancy, dur flat -> occupancy not the limiter.
// R12/R13: shfl butterfly = ds_swizzle (LDS pipe) -> +10us. REVERTED.
// R14: PV via K=16 MFMA, no P movement: MfmaUtil 24->39, VALUBusy 31->46, dur STILL ~53.
//   -> neither pipe nor P-path latency binds; the invariant across R1/R14 is the per-wave
//      LDS fragment read volume (8KB/wave/kt, 4x redundant across qh) + exp2 VALU.
// R15: re-shard waves to (qh:2 x ky:4): 64 q + 16-key slice per wave. LDS frag reads
// halve (2 b128 K + 4 b64 V = 4KB/wave/kt), exp2/pack halves, 4 independent t-chains
// (double ILP), MFMA totals unchanged. PV K=16 is natural for 16-key slices (no V key
// interleave needed). Epilogue: 4-way ky merge, one t-round at a time.
__global__ __launch_bounds__(512, 2) void flash_attn(
    const bf16* __restrict__ Q, const bf16* __restrict__ K,
    const bf16* __restrict__ Vt, bf16* __restrict__ ctx) {
  // staging: K[ky][buf] 1KB slices at (ky*2+buf)*1024, V at 8192+same. 32 KB total.
  // merge redbuf aliases smem: 6 regions x 16 rows x 68 floats = 26112 B <= 32 KB.
  __shared__ __align__(16) bf16 smem[16384];
  __shared__ float lredm[2][3][16];
  float* redbuf = (float*)smem;

  const int tid = threadIdx.x;
  const int wave = tid >> 6, lane = tid & 63;
  const int c15 = lane & 15, g = lane >> 4;
  const int qh = wave >> 2, ky = wave & 3;  // qh 0..1 (64-q slice), ky 0..3 (16-key slice)
  const int bh = blockIdx.x & 31;   // b*16+h (XCD = bh%8)
  const int qt = blockIdx.x >> 5;   // 128-query tile, 0..15
  const size_t hb = (size_t)bh * S_N * DK;
  const bf16* Qb = Q + hb;
  const bf16* Kb = K + hb;
  const bf16* Vb = Vt + hb;  // [d][s] rows, stride S_N

  // Q B-frags: 4 q-tiles of 16 for this wave's 64-query slice
  const int qb = qt * 128 + qh * 64;
  bf16x8 qf[4][2];
#pragma unroll
  for (int t = 0; t < 4; ++t) {
    qf[t][0] = *(const bf16x8*)&Qb[(size_t)(qb + t * 16 + c15) * DK + g * 8];
    qf[t][1] = *(const bf16x8*)&Qb[(size_t)(qb + t * 16 + c15) * DK + 32 + g * 8];
  }

  f32x4 O[4][4] = {};  // [q-tile][d-tile]: O^T row d = nt*16+g*4+r, col q = c15
  float l[4] = {0.f, 0.f, 0.f, 0.f};
  const int sw = c15 & 7;                    // K granule-XOR swizzle key
  const int vsw = (g >> 1) ^ ((c15 >> 2) & 1);  // V 16B-granule swizzle

  constexpr int NTK = S_N / 64;  // 32 iters; each wave sees its ky 16-key slice
  // K slice: 16 keys x 64 d, granule(16B) cd = cp ^ (row&7). V slice: 64 d rows x 16 keys,
  // 2 granules/row, swizzled g16 ^ ((row>>2)&1) to break the 32B-row bank aliasing.
#define STAGE(kt_, b_)                                                            \
  if (qh == 0) { /* stage K slice ky */                                           \
    const bf16* Ksrc = Kb + (size_t)((kt_)*64 + ky * 16) * DK;                    \
    _Pragma("unroll") for (int c = 0; c < 2; ++c) {                               \
      const int gi = c * 64 + lane;                                               \
      const int rr = gi >> 3, cp = gi & 7;                                        \
      gl_lds16(Ksrc + (size_t)rr * 64 + (cp ^ (rr & 7)) * 8,                      \
               &smem[(ky * 2 + (b_)) * 1024 + c * 512]);                          \
    }                                                                             \
  } else { /* stage V slice ky */                                                 \
    const bf16* Vsrc = Vb + (kt_)*64 + ky * 16;                                   \
    _Pragma("unroll") for (int c = 0; c < 2; ++c) {                               \
      const int gi = c * 64 + lane;                                               \
      const int rv = gi >> 1, gv = gi & 1;                                        \
      gl_lds16(Vsrc + (size_t)rv * S_N + (gv ^ ((rv >> 2) & 1)) * 8,              \
               &smem[8192 + (ky * 2 + (b_)) * 1024 + c * 512]);                   \
    }                                                                             \
  }

  STAGE(0, 0)
  for (int kt = 0; kt < NTK; ++kt) {
    __syncthreads();  // tile kt resident (its loads were issued one full phase ago)
    if (kt + 1 < NTK) STAGE(kt + 1, (kt + 1) & 1)
    const bf16* Kl = &smem[(ky * 2 + (kt & 1)) * 1024];
    const bf16* Vl = &smem[8192 + (ky * 2 + (kt & 1)) * 1024];

    // K A-frags: 16 keys x 2 d-halves (granule-XOR swizzle round-trips the staging cd)
    bf16x8 kf0 = *(const bf16x8*)&Kl[c15 * 64 + ((g ^ sw) * 8)];
    bf16x8 kf1 = *(const bf16x8*)&Kl[c15 * 64 + (((4 | g) ^ sw) * 8)];
    // V A-frags: 4 d-subtiles, keys g*4..g*4+3 (8B each, swizzle round-trip)
    s16x4 vf[4];
#pragma unroll
    for (int nt = 0; nt < 4; ++nt)
      vf[nt] = *(const s16x4*)&Vl[(nt * 16 + c15) * 16 + vsw * 8 + (g & 1) * 4];

    // per q-tile: S^T = K·Q^T (16 keys x 16 q) -> exp2 -> PV via K=16 MFMA (no P movement)
#pragma unroll
    for (int t = 0; t < 4; ++t) {
      f32x4 s = {};
      s = MFMA16(kf0, qf[t][0], s);
      s = MFMA16(kf1, qf[t][1], s);
      union PK { s16x4 s4; bf16 h[4]; } Pk;
      float p0 = EXP2F(s[0]), p1 = EXP2F(s[1]), p2 = EXP2F(s[2]), p3 = EXP2F(s[3]);
      l[t] += (p0 + p1) + (p2 + p3);
      Pk.h[0] = (bf16)p0; Pk.h[1] = (bf16)p1; Pk.h[2] = (bf16)p2; Pk.h[3] = (bf16)p3;
      // Pk = P[keys 4g..4g+3][q=c15] = K=16 B-frag; vf[nt] = V A-frag (same keys).
#pragma unroll
      for (int nt = 0; nt < 4; ++nt)
        O[t][nt] = MFMA16K16(vf[nt], Pk.s4, O[t][nt]);
    }
  }
#undef STAGE

  // own-wave l reduction (sum over g-lanes sharing c15) -> l over this wave's 16 keys
#pragma unroll
  for (int t = 0; t < 4; ++t) {
    l[t] += __shfl_xor(l[t], 16);
    l[t] += __shfl_xor(l[t], 32);
  }

  // 4-way ky merge, one t-round at a time (redbuf aliases staging LDS; epilogue-only).
  const int bb = bh >> 4, hh = bh & 15;
#pragma unroll
  for (int t = 0; t < 4; ++t) {
    __syncthreads();  // staging reads done (t=0) / previous round consumed (t>0)
    if (ky != 0) {
      const int reg = qh * 3 + ky - 1;
#pragma unroll
      for (int nt = 0; nt < 4; ++nt)
        *(f32x4*)&redbuf[(reg * 16 + c15) * 68 + nt * 16 + g * 4] = O[t][nt];
      if (g == 0) lredm[qh][ky - 1][c15] = l[t];
    }
    __syncthreads();
    if (ky == 0) {
      const float inv =
          1.0f / (l[t] + lredm[qh][0][c15] + lredm[qh][1][c15] + lredm[qh][2][c15]);
      const size_t base = ((size_t)(bb * S_N + qb + t * 16 + c15) * H_N + hh) * DK;
#pragma unroll
      for (int nt = 0; nt < 4; ++nt) {
        f32x4 o = O[t][nt];
#pragma unroll
        for (int rg = 0; rg < 3; ++rg)
          o += *(const f32x4*)&redbuf[((qh * 3 + rg) * 16 + c15) * 68 + nt * 16 + g * 4];
        bf16x4 v4;
#pragma unroll
        for (int r = 0; r < 4; ++r) v4[r] = (bf16)(o[r] * inv);
        *(bf16x4*)&ctx[base + nt * 16 + g * 4] = v4;
      }
    }
  }
}

// ---------------- output projection: out = ctx @ Wo^T (fp32), 64x128 tiles ----------------
__global__ __launch_bounds__(256) void gemm_out(
    const bf16* __restrict__ Cx, const bf16* __restrict__ Wo,
    float* __restrict__ out) {
  __shared__ __align__(16) bf16 As[64 * 32];
  __shared__ __align__(16) bf16 Bs[128 * 32];
  const int tid = threadIdx.x;
  const int wave = tid >> 6, lane = tid & 63;
  const int c15 = lane & 15, g = lane >> 4;
  const int mw = (wave & 1) * 32, nw = (wave >> 1) * 64;
  const int row0 = blockIdx.x * 64;
  const int n0 = blockIdx.y * 128;
  const bf16* Asrc = Cx + (size_t)row0 * DM;
  const bf16* Bsrc = Wo + (size_t)n0 * DM;
  const int giA = wave * 64 + lane;
  const int rA = giA >> 2, cA = (giA & 3) * 8;
  const int giB = wave * 128 + lane;
  const int rB0 = giB >> 2, cB0 = (giB & 3) * 8;
  const int rB1 = (giB + 64) >> 2, cB1 = ((giB + 64) & 3) * 8;

  f32x4 acc[2][4] = {};
  for (int kt = 0; kt < DM / 32; ++kt) {
    const int k0 = kt * 32;
    __syncthreads();
    gl_lds16(Asrc + (size_t)rA * DM + k0 + cA, &As[wave * 512]);
    gl_lds16(Bsrc + (size_t)rB0 * DM + k0 + cB0, &Bs[wave * 1024]);
    gl_lds16(Bsrc + (size_t)rB1 * DM + k0 + cB1, &Bs[wave * 1024 + 512]);
    __syncthreads();
    bf16x8 af[2], bfr[4];
#pragma unroll
    for (int t = 0; t < 2; ++t)
      af[t] = *(const bf16x8*)&As[(mw + t * 16 + c15) * 32 + g * 8];
#pragma unroll
    for (int t = 0; t < 4; ++t)
      bfr[t] = *(const bf16x8*)&Bs[(nw + t * 16 + c15) * 32 + g * 8];
#pragma unroll
    for (int mt = 0; mt < 2; ++mt)
#pragma unroll
      for (int nt = 0; nt < 4; ++nt)
        acc[mt][nt] = MFMA16(af[mt], bfr[nt], acc[mt][nt]);
  }
#pragma unroll
  for (int mt = 0; mt < 2; ++mt)
#pragma unroll
    for (int r = 0; r < 4; ++r) {
      const int row = row0 + mw + mt * 16 + g * 4 + r;
#pragma unroll
      for (int nt = 0; nt < 4; ++nt)
        out[(size_t)row * DM + n0 + nw + nt * 16 + c15] = acc[mt][nt][r];
    }
}

extern "C" void kernel_launch(void* const* d_in, const int* in_sizes, int n_in,
                              void* d_out, int out_size, void* d_ws, size_t ws_size,
                              hipStream_t stream) {
  const float* hs = (const float*)d_in[0];
  const int* pos = (const int*)d_in[1];
  const float* wq = (const float*)d_in[2];
  const float* wk = (const float*)d_in[3];
  const float* wv = (const float*)d_in[4];
  const float* wo = (const float*)d_in[5];
  float* out = (float*)d_out;
  bf16* ws = (bf16*)d_ws;
  float2* tab = (float2*)(ws + OFF_C);  // aliases ctx region; disjoint lifetime

  cast_all<<<8192, 256, 0, stream>>>(hs, wq, wk, wv, wo, ws, tab);

  dim3 gq(M_N / 128, (3 * DM) / 128);
  gemm_qkv_rope<<<gq, 256, 0, stream>>>(ws + OFF_X, ws + OFF_W, pos, tab,
                                        ws + OFF_Q, ws + OFF_K, ws + OFF_V);

  // grid 512: blockIdx = qt*32 + bh (128-query tiles, XCD-local per head); 512 threads = 8 waves
  flash_attn<<<B_N * H_N * (S_N / 128), 512, 0, stream>>>(
      ws + OFF_Q, ws + OFF_K, ws + OFF_V, ws + OFF_C);

  dim3 go(M_N / 64, DM / 128);
  gemm_out<<<go, 256, 0, stream>>>(ws + OFF_C, ws + OFF_W + 3 * NW, out);
}

// Round 6
// 202.520 us; speedup vs baseline: 1.0450x; 1.0450x over previous
//
#include <hip/hip_runtime.h>
#include <hip/hip_bf16.h>
#include <math.h>

typedef __bf16 bf16;
typedef __bf16 bf16x8 __attribute__((ext_vector_type(8)));
typedef __bf16 bf16x4 __attribute__((ext_vector_type(4)));
typedef float f32x4 __attribute__((ext_vector_type(4)));
typedef short s16x4 __attribute__((ext_vector_type(4)));

#define MFMA16(a, b, c) __builtin_amdgcn_mfma_f32_16x16x32_bf16((a), (b), (c), 0, 0, 0)
// K=16 bf16 MFMA: B-frag layout B[k=g*4+j][col=c15] matches QK^T C-layout directly.
#define MFMA16K16(a, b, c) __builtin_amdgcn_mfma_f32_16x16x16bf16_1k((a), (b), (c), 0, 0, 0)
#define EXP2F(x) __builtin_amdgcn_exp2f(x)  // v_exp_f32: computes 2^x

// async global->LDS, 16B per lane; LDS dest = (wave-uniform) base + lane*16
__device__ __forceinline__ void gl_lds16(const bf16* g, bf16* l) {
  __builtin_amdgcn_global_load_lds(
      (const __attribute__((address_space(1))) void*)g,
      (__attribute__((address_space(3))) void*)l, 16, 0, 0);
}

// problem dims
static constexpr int B_N = 2, S_N = 2048, DM = 1024, H_N = 16, DK = 64;
static constexpr int M_N = B_N * S_N;             // 4096
static constexpr size_t NX = (size_t)M_N * DM;    // 4M elements
static constexpr size_t NW = (size_t)DM * DM;     // 1M elements
// workspace layout (bf16 elements)
static constexpr size_t OFF_X = 0;
static constexpr size_t OFF_W = NX;               // Wq,Wk,Wv,Wo
static constexpr size_t OFF_Q = OFF_W + 4 * NW;   // Q [b,h,s,d] (pre-scaled by log2e/8, roped)
static constexpr size_t OFF_K = OFF_Q + NX;       // K [b,h,s,d] (roped)
static constexpr size_t OFF_V = OFF_K + NX;       // V^T [b,h,d,s]
static constexpr size_t OFF_C = OFF_V + NX;       // ctx [b,s,h*d]; rope table aliases its head
// total 24M bf16 = 48 MB

// ---------------- fp32 -> bf16 cast + RoPE table (fused) ----------------
__global__ __launch_bounds__(256) void cast_all(
    const float* __restrict__ x, const float* __restrict__ wq,
    const float* __restrict__ wk, const float* __restrict__ wv,
    const float* __restrict__ wo, bf16* __restrict__ dst,
    float2* __restrict__ tab) {
  size_t i = ((size_t)blockIdx.x * 256 + threadIdx.x) * 4;
  const float* src;
  size_t off;
  if (i < NX) {
    src = x; off = i;
  } else {
    size_t e = i - NX;
    int wi = (int)(e >> 20);
    src = (wi == 0) ? wq : (wi == 1) ? wk : (wi == 2) ? wv : wo;
    off = e & (NW - 1);
  }
  float4 v = *(const float4*)(src + off);
  bf16x4 o = {(bf16)v.x, (bf16)v.y, (bf16)v.z, (bf16)v.w};
  *(bf16x4*)(dst + i) = o;
  if (blockIdx.x < 256) {
    int t = blockIdx.x * 256 + threadIdx.x;  // 65536 entries
    int s = t >> 5, j = t & 31;
    float invf = powf(10000.f, -(float)(2 * j) / 64.f);
    float sn, cs;
    sincosf((float)s * invf, &sn, &cs);
    tab[t] = make_float2(cs, sn);
  }
}

// ---------------- QKV GEMM (M=4096,N=3072,K=1024) + fused RoPE, V written transposed ----------------
__global__ __launch_bounds__(256) void gemm_qkv_rope(
    const bf16* __restrict__ X, const bf16* __restrict__ W3,
    const int* __restrict__ pos_ids, const float2* __restrict__ tab,
    bf16* __restrict__ Qo, bf16* __restrict__ Ko, bf16* __restrict__ Vt) {
  __shared__ __align__(16) bf16 As[128 * 32];
  __shared__ __align__(16) bf16 Bs[128 * 32];
  const int tid = threadIdx.x;
  const int wave = tid >> 6, lane = tid & 63;
  const int c15 = lane & 15, g = lane >> 4;
  const int mw = (wave & 1) * 64, nw = (wave >> 1) * 64;
  const int row0 = blockIdx.x * 128;
  const int n0 = blockIdx.y * 128;
  const bf16* Asrc = X + (size_t)row0 * DM;
  const bf16* Bsrc = W3 + (size_t)n0 * DM;
  const int srA = wave * 32 + (lane >> 2);
  const int cph = lane & 3;

  f32x4 acc[4][4] = {};
  for (int kt = 0; kt < DM / 32; ++kt) {
    const int k0 = kt * 32;
    __syncthreads();
#pragma unroll
    for (int c = 0; c < 2; ++c) {
      const int r = srA + c * 16;
      gl_lds16(Asrc + (size_t)r * DM + k0 + cph * 8, &As[wave * 1024 + c * 512]);
      gl_lds16(Bsrc + (size_t)r * DM + k0 + cph * 8, &Bs[wave * 1024 + c * 512]);
    }
    __syncthreads();
    bf16x8 af[4], bfr[4];
#pragma unroll
    for (int t = 0; t < 4; ++t)
      af[t] = *(const bf16x8*)&As[(mw + t * 16 + c15) * 32 + g * 8];
#pragma unroll
    for (int t = 0; t < 4; ++t)
      bfr[t] = *(const bf16x8*)&Bs[(nw + t * 16 + c15) * 32 + g * 8];
#pragma unroll
    for (int mt = 0; mt < 4; ++mt)
#pragma unroll
      for (int nt = 0; nt < 4; ++nt)
        acc[mt][nt] = MFMA16(af[mt], bfr[nt], acc[mt][nt]);
  }

  // epilogue: C/D col = nt*16+c15, row = g*4+r
  const int Wsel = n0 >> 10;             // 0=q, 1=k, 2=v
  const int colbase = (n0 & 1023) + nw;  // multiple of 64 -> one head
  const int h = colbase >> 6;
  if (Wsel == 2) {
#pragma unroll
    for (int mt = 0; mt < 4; ++mt) {
      const int srow = row0 + mw + mt * 16 + g * 4;
      const int bb = srow >> 11, ss = srow & 2047;
      const size_t vb = ((size_t)(bb * H_N + h) * DK) * S_N + ss;
#pragma unroll
      for (int nt = 0; nt < 4; ++nt) {
        bf16x4 v4;
#pragma unroll
        for (int r = 0; r < 4; ++r) v4[r] = (bf16)acc[mt][nt][r];
        *(bf16x4*)&Vt[vb + (size_t)(nt * 16 + c15) * S_N] = v4;
      }
    }
  } else {
    bf16* dst = (Wsel == 0) ? Qo : Ko;
    // Q pre-scale folds 1/sqrt(64) AND log2(e) so flash can use exp2 directly.
    const float sc = (Wsel == 0) ? 0.125f * 1.44269504088896f : 1.0f;
#pragma unroll
    for (int mt = 0; mt < 4; ++mt) {
#pragma unroll
      for (int r = 0; r < 4; ++r) {
        const int row = row0 + mw + mt * 16 + g * 4 + r;
        const int bb = row >> 11, ss = row & 2047;
        const int pos = pos_ids[row];
        const float2 c0 = tab[pos * 32 + c15];       // freq j = c15
        const float2 c1 = tab[pos * 32 + 16 + c15];  // freq j = 16+c15
        const size_t base = ((size_t)(bb * H_N + h) * S_N + ss) * DK;
#pragma unroll
        for (int ntp = 0; ntp < 2; ++ntp) {
          float x1 = acc[mt][ntp][r], x2 = acc[mt][ntp + 2][r];
          float cs = ntp ? c1.x : c0.x, sn = ntp ? c1.y : c0.y;
          dst[base + ntp * 16 + c15] = (bf16)((x1 * cs - x2 * sn) * sc);
          dst[base + ntp * 16 + c15 + 32] = (bf16)((x2 * cs + x1 * sn) * sc);
        }
      }
    }
  }
}

// ---------------- flash attention: BARRIER-FREE main loop ----------------
// Evidence R1/R14/R15: three structures, same ~53us floor; R14 MFMA-busy (39% x 53.4 =
// 20.8us) == K16-PV MFMA floor (20.7us) -> ~32us is pure sync convoy (all-wave vmcnt(0)
// drain + 2 barriers per kt; the documented 2-phase stall, m233).
// R16: remove ALL __syncthreads from the loop. 8 waves = (qh:2 x 64-q) x (ky:4 x 16-key);
// each wave stages its OWN K and V slice (private 8KB: 2 bufs x (2KB K + 2KB V)),
// depth-2 prefetch, self-synced with counted vmcnt(4) (never 0 mid-loop) + lgkmcnt(0)
// fence before the WAR overwrite. No cross-wave deps -> no convoy. Cost: K/V fetched by
// 2 waves each (qh 0/1) -> 2x L2 traffic, well under budget.
// V bank fix (R15 bug): bijective 16B-granule XOR on the GLOBAL source (linear LDS dest,
// both-sides-or-neither): gi=(2r|h)^(((r>>2)&3)<<1); inverse r=(y&~3)|((y^(y>>2))&3),
// h=gi&1. Spreads the 4 b64-colliding lanes across 4 distinct slots -> conflict-free.
__global__ __launch_bounds__(512, 2) void flash_attn(
    const bf16* __restrict__ Q, const bf16* __restrict__ K,
    const bf16* __restrict__ Vt, bf16* __restrict__ ctx) {
  // per-wave region: wave*4096 elem; K bufs at +0/+1024, V bufs at +2048/+3072.
  // 8 waves x 8KB = 64KB; 2 blocks/CU = 128KB <= 160KB.
  // merge redbuf aliases smem (6 regions x 16 rows x 68 floats = 26112B <= 64KB).
  __shared__ __align__(16) bf16 smem[32768];
  __shared__ float lredm[2][3][16];
  float* redbuf = (float*)smem;

  const int tid = threadIdx.x;
  const int wave = tid >> 6, lane = tid & 63;
  const int c15 = lane & 15, g = lane >> 4;
  const int qh = wave >> 2, ky = wave & 3;  // qh 0..1 (64-q slice), ky 0..3 (16-key slice)
  const int ky16 = ky * 16;
  const int Wb = wave * 4096;
  const int bh = blockIdx.x & 31;   // b*16+h (XCD = bh%8)
  const int qt = blockIdx.x >> 5;   // 128-query tile, 0..15
  const size_t hb = (size_t)bh * S_N * DK;
  const bf16* Qb = Q + hb;
  const bf16* Kb = K + hb;
  const bf16* Vb = Vt + hb;  // [d][s] rows, stride S_N

  // Q B-frags: 4 q-tiles of 16 for this wave's 64-query slice
  const int qb = qt * 128 + qh * 64;
  bf16x8 qf[4][2];
#pragma unroll
  for (int t = 0; t < 4; ++t) {
    qf[t][0] = *(const bf16x8*)&Qb[(size_t)(qb + t * 16 + c15) * DK + g * 8];
    qf[t][1] = *(const bf16x8*)&Qb[(size_t)(qb + t * 16 + c15) * DK + 32 + g * 8];
  }
  // retire qf before staging so in-loop waitcnt scores stay clean
  asm volatile("s_waitcnt vmcnt(0)" ::: "memory");

  f32x4 O[4][4] = {};  // [q-tile][d-tile]: O^T row d = nt*16+g*4+r, col q = c15
  float l[4] = {0.f, 0.f, 0.f, 0.f};
  const int sw = c15 & 7;  // K granule-XOR swizzle key

  constexpr int NTK = S_N / 64;  // 32 iters; each wave sees its ky 16-key slice
  // own-wave staging: K slice 16 keys x 64 d (granule cd = cp ^ (row&7));
  // V slice 64 d-rows x 16 keys, granule-swizzled via gi-inverse on the global source.
#define STAGE(kt_, b_) {                                                          \
    const bf16* Ksrc = Kb + (size_t)((kt_)*64 + ky16) * DK;                       \
    _Pragma("unroll") for (int c = 0; c < 2; ++c) {                               \
      const int gi = c * 64 + lane;                                               \
      const int rr = gi >> 3, cp = gi & 7;                                        \
      gl_lds16(Ksrc + (size_t)rr * DK + (cp ^ (rr & 7)) * 8,                      \
               &smem[Wb + (b_)*1024 + c * 512]);                                  \
    }                                                                             \
    const bf16* Vsrc = Vb + (kt_)*64 + ky16;                                      \
    _Pragma("unroll") for (int c = 0; c < 2; ++c) {                               \
      const int gi = c * 64 + lane;                                               \
      const int h = gi & 1, y = gi >> 1;                                          \
      const int rv = (y & ~3) | ((y ^ (y >> 2)) & 3);                             \
      gl_lds16(Vsrc + (size_t)rv * S_N + h * 8,                                   \
               &smem[Wb + 2048 + (b_)*1024 + c * 512]);                           \
    }                                                                             \
  }

  STAGE(0, 0)
  STAGE(1, 1)
  for (int kt = 0; kt < NTK; ++kt) {
    // tile kt resident: 8 loads outstanding (kt, kt+1); drain kt's 4 (counted, not 0)
    if (kt + 1 < NTK) {
      asm volatile("s_waitcnt vmcnt(4)" ::: "memory");
    } else {
      asm volatile("s_waitcnt vmcnt(0)" ::: "memory");
    }
    __builtin_amdgcn_sched_barrier(0);
    const bf16* Kl = &smem[Wb + (kt & 1) * 1024];
    const bf16* Vl = &smem[Wb + 2048 + (kt & 1) * 1024];

    // K A-frags: 16 keys x 2 d-halves (granule-XOR swizzle round-trips the staging cd)
    bf16x8 kf0 = *(const bf16x8*)&Kl[c15 * 64 + ((g ^ sw) * 8)];
    bf16x8 kf1 = *(const bf16x8*)&Kl[c15 * 64 + (((4 | g) ^ sw) * 8)];
    // V A-frags: 4 d-subtiles, keys 4g..4g+3 at swizzled granule (2 lanes/slot, 2 banks)
    s16x4 vf[4];
#pragma unroll
    for (int nt = 0; nt < 4; ++nt) {
      const int r = nt * 16 + c15;
      const int gi = ((2 * r) | (g >> 1)) ^ (((r >> 2) & 3) << 1);
      vf[nt] = *(const s16x4*)&Vl[gi * 8 + (g & 1) * 4];
    }
    // frags in regs -> safe to overwrite this buffer with tile kt+2
    asm volatile("s_waitcnt lgkmcnt(0)" ::: "memory");
    __builtin_amdgcn_sched_barrier(0);
    if (kt + 2 < NTK) STAGE(kt + 2, kt & 1)

    // per q-tile: S^T = K.Q^T (16 keys x 16 q) -> exp2 -> PV via K=16 MFMA
#pragma unroll
    for (int t = 0; t < 4; ++t) {
      f32x4 s = {};
      s = MFMA16(kf0, qf[t][0], s);
      s = MFMA16(kf1, qf[t][1], s);
      union PK { s16x4 s4; bf16 h[4]; } Pk;
      float p0 = EXP2F(s[0]), p1 = EXP2F(s[1]), p2 = EXP2F(s[2]), p3 = EXP2F(s[3]);
      l[t] += (p0 + p1) + (p2 + p3);
      Pk.h[0] = (bf16)p0; Pk.h[1] = (bf16)p1; Pk.h[2] = (bf16)p2; Pk.h[3] = (bf16)p3;
      // Pk = P[keys 4g..4g+3][q=c15] = K=16 B-frag; vf[nt] = V A-frag (same keys).
#pragma unroll
      for (int nt = 0; nt < 4; ++nt)
        O[t][nt] = MFMA16K16(vf[nt], Pk.s4, O[t][nt]);
    }
  }
#undef STAGE

  // own-wave l reduction (sum over g-lanes sharing c15) -> l over this wave's 16 keys
#pragma unroll
  for (int t = 0; t < 4; ++t) {
    l[t] += __shfl_xor(l[t], 16);
    l[t] += __shfl_xor(l[t], 32);
  }

  // 4-way ky merge, one t-round at a time (redbuf aliases staging LDS; epilogue-only).
  const int bb = bh >> 4, hh = bh & 15;
#pragma unroll
  for (int t = 0; t < 4; ++t) {
    __syncthreads();  // staging reads done (t=0) / previous round consumed (t>0)
    if (ky != 0) {
      const int reg = qh * 3 + ky - 1;
#pragma unroll
      for (int nt = 0; nt < 4; ++nt)
        *(f32x4*)&redbuf[(reg * 16 + c15) * 68 + nt * 16 + g * 4] = O[t][nt];
      if (g == 0) lredm[qh][ky - 1][c15] = l[t];
    }
    __syncthreads();
    if (ky == 0) {
      const float inv =
          1.0f / (l[t] + lredm[qh][0][c15] + lredm[qh][1][c15] + lredm[qh][2][c15]);
      const size_t base = ((size_t)(bb * S_N + qb + t * 16 + c15) * H_N + hh) * DK;
#pragma unroll
      for (int nt = 0; nt < 4; ++nt) {
        f32x4 o = O[t][nt];
#pragma unroll
        for (int rg = 0; rg < 3; ++rg)
          o += *(const f32x4*)&redbuf[((qh * 3 + rg) * 16 + c15) * 68 + nt * 16 + g * 4];
        bf16x4 v4;
#pragma unroll
        for (int r = 0; r < 4; ++r) v4[r] = (bf16)(o[r] * inv);
        *(bf16x4*)&ctx[base + nt * 16 + g * 4] = v4;
      }
    }
  }
}

// ---------------- output projection: out = ctx @ Wo^T (fp32), 64x128 tiles ----------------
__global__ __launch_bounds__(256) void gemm_out(
    const bf16* __restrict__ Cx, const bf16* __restrict__ Wo,
    float* __restrict__ out) {
  __shared__ __align__(16) bf16 As[64 * 32];
  __shared__ __align__(16) bf16 Bs[128 * 32];
  const int tid = threadIdx.x;
  const int wave = tid >> 6, lane = tid & 63;
  const int c15 = lane & 15, g = lane >> 4;
  const int mw = (wave & 1) * 32, nw = (wave >> 1) * 64;
  const int row0 = blockIdx.x * 64;
  const int n0 = blockIdx.y * 128;
  const bf16* Asrc = Cx + (size_t)row0 * DM;
  const bf16* Bsrc = Wo + (size_t)n0 * DM;
  const int giA = wave * 64 + lane;
  const int rA = giA >> 2, cA = (giA & 3) * 8;
  const int giB = wave * 128 + lane;
  const int rB0 = giB >> 2, cB0 = (giB & 3) * 8;
  const int rB1 = (giB + 64) >> 2, cB1 = ((giB + 64) & 3) * 8;

  f32x4 acc[2][4] = {};
  for (int kt = 0; kt < DM / 32; ++kt) {
    const int k0 = kt * 32;
    __syncthreads();
    gl_lds16(Asrc + (size_t)rA * DM + k0 + cA, &As[wave * 512]);
    gl_lds16(Bsrc + (size_t)rB0 * DM + k0 + cB0, &Bs[wave * 1024]);
    gl_lds16(Bsrc + (size_t)rB1 * DM + k0 + cB1, &Bs[wave * 1024 + 512]);
    __syncthreads();
    bf16x8 af[2], bfr[4];
#pragma unroll
    for (int t = 0; t < 2; ++t)
      af[t] = *(const bf16x8*)&As[(mw + t * 16 + c15) * 32 + g * 8];
#pragma unroll
    for (int t = 0; t < 4; ++t)
      bfr[t] = *(const bf16x8*)&Bs[(nw + t * 16 + c15) * 32 + g * 8];
#pragma unroll
    for (int mt = 0; mt < 2; ++mt)
#pragma unroll
      for (int nt = 0; nt < 4; ++nt)
        acc[mt][nt] = MFMA16(af[mt], bfr[nt], acc[mt][nt]);
  }
#pragma unroll
  for (int mt = 0; mt < 2; ++mt)
#pragma unroll
    for (int r = 0; r < 4; ++r) {
      const int row = row0 + mw + mt * 16 + g * 4 + r;
#pragma unroll
      for (int nt = 0; nt < 4; ++nt)
        out[(size_t)row * DM + n0 + nw + nt * 16 + c15] = acc[mt][nt][r];
    }
}

extern "C" void kernel_launch(void* const* d_in, const int* in_sizes, int n_in,
                              void* d_out, int out_size, void* d_ws, size_t ws_size,
                              hipStream_t stream) {
  const float* hs = (const float*)d_in[0];
  const int* pos = (const int*)d_in[1];
  const float* wq = (const float*)d_in[2];
  const float* wk = (const float*)d_in[3];
  const float* wv = (const float*)d_in[4];
  const float* wo = (const float*)d_in[5];
  float* out = (float*)d_out;
  bf16* ws = (bf16*)d_ws;
  float2* tab = (float2*)(ws + OFF_C);  // aliases ctx region; disjoint lifetime

  cast_all<<<8192, 256, 0, stream>>>(hs, wq, wk, wv, wo, ws, tab);

  dim3 gq(M_N / 128, (3 * DM) / 128);
  gemm_qkv_rope<<<gq, 256, 0, stream>>>(ws + OFF_X, ws + OFF_W, pos, tab,
                                        ws + OFF_Q, ws + OFF_K, ws + OFF_V);

  // grid 512: blockIdx = qt*32 + bh (128-query tiles, XCD-local per head); 512 threads = 8 waves
  flash_attn<<<B_N * H_N * (S_N / 128), 512, 0, stream>>>(
      ws + OFF_Q, ws + OFF_K, ws + OFF_V, ws + OFF_C);

  dim3 go(M_N / 64, DM / 128);
  gemm_out<<<go, 256, 0, stream>>>(ws + OFF_C, ws + OFF_W + 3 * NW, out);
}